// Round 25
// baseline (5206.967 us; speedup 1.0000x reference)
//
#include <hip/hip_runtime.h>
#include <cmath>

#define NB   256
#define NT   64
#define DATA 256
#define DD   264
#define NSUB 4
#define NTH  1024
#define PI_F 3.14159265358979323846f

typedef _Float16 h2 __attribute__((ext_vector_type(2)));
typedef __fp16   g2 __attribute__((ext_vector_type(2)));

// ---- d_ws u32 offsets: f16 pairs ALONG K (u32 [kk][j] = {W[2kk][j],W[2kk+1][j]})
#define WS_W0  0                        // [136][256]
#define WS_W1  (WS_W0 + 136 * 256)      // [128][256]
#define WS_W2  (WS_W1 + 128 * 256)      // [128][256]
#define WS_W3  (WS_W2 + 128 * 256)      // [128][256]
#define WS_W3T (WS_W3 + 128 * 256)      // [128][8]  tail j=256..263

// ---- LDS word offsets ----
#define NW1LDS 124                        // W1 pairs resident in LDS
#define L_W1   0                          // [124][256] u32 = 126,976 B
#define L_PSA  (L_W1 + NW1LDS * 256)      // [16][256] fp32 partials (buffer A)
#define L_PSB  (L_PSA + 16 * 256)         // [16][256] fp32 partials (buffer B)
#define L_PT   (L_PSB + 16 * 256)         // [16][8]   fp32 tail partials
#define L_FPH  (L_PT + 16 * 8)            // [16][9]   packed f16 activations
#define LDS_WORDS (L_FPH + 16 * 9)        // 40,208 words = 160,832 B -> 1 blk/CU

__device__ __forceinline__ float dot2(unsigned wu, unsigned hu, float c) {
  h2 a = __builtin_bit_cast(h2, wu);
  h2 b = __builtin_bit_cast(h2, hu);
#if __has_builtin(__builtin_amdgcn_fdot2)
  return __builtin_amdgcn_fdot2(a, b, c, false);
#else
  return c + (float)a[0] * (float)b[0] + (float)a[1] * (float)b[1];
#endif
}
__device__ __forceinline__ unsigned pkh(float a, float b) {
#if __has_builtin(__builtin_amdgcn_cvt_pkrtz)
  g2 v = __builtin_amdgcn_cvt_pkrtz(a, b);
  return __builtin_bit_cast(unsigned, v);
#else
  h2 v; v[0] = (_Float16)a; v[1] = (_Float16)b;
  return __builtin_bit_cast(unsigned, v);
#endif
}
__device__ __forceinline__ unsigned pkh_rne(float a, float b) {
  h2 v; v[0] = (_Float16)a; v[1] = (_Float16)b;
  return __builtin_bit_cast(unsigned, v);
}

#define DOT4(acc, u, hp)                                                      \
  acc.x = dot2(u.x, hp, acc.x);                                               \
  acc.y = dot2(u.y, hp, acc.y);                                               \
  acc.z = dot2(u.z, hp, acc.z);                                               \
  acc.w = dot2(u.w, hp, acc.w);

__global__ void prep(const float* __restrict__ W0, const float* __restrict__ W1,
                     const float* __restrict__ W2, const float* __restrict__ W3,
                     unsigned* __restrict__ wsu) {
  int tid = blockIdx.x * blockDim.x + threadIdx.x;
  int stride = gridDim.x * blockDim.x;
  for (int i = tid; i < 136 * 256; i += stride) {
    int kk = i >> 8, j = i & 255;
    int k0 = 2 * kk, k1 = 2 * kk + 1;
    float lo = (k0 < DD) ? W0[j * DD + k0] : 0.f;
    float hi = (k1 < DD) ? W0[j * DD + k1] : 0.f;
    wsu[WS_W0 + i] = pkh_rne(lo, hi);
  }
  for (int i = tid; i < 128 * 256; i += stride) {
    int kk = i >> 8, j = i & 255;
    wsu[WS_W1 + i] = pkh_rne(W1[j * 256 + 2 * kk], W1[j * 256 + 2 * kk + 1]);
    wsu[WS_W2 + i] = pkh_rne(W2[j * 256 + 2 * kk], W2[j * 256 + 2 * kk + 1]);
    wsu[WS_W3 + i] = pkh_rne(W3[j * 256 + 2 * kk], W3[j * 256 + 2 * kk + 1]);
  }
  for (int i = tid; i < 128 * 8; i += stride) {     // W3 tail j=256..263
    int kk = i >> 3, c = 256 + (i & 7);
    wsu[WS_W3T + i] = pkh_rne(W3[c * 256 + 2 * kk], W3[c * 256 + 2 * kk + 1]);
  }
}

// R25 = R24 with THE bug fixed: bias was seeded per-lane BEFORE the 4-lane
// butterfly reduce -> counted 4x on every layer (R23/R24's identical 0.367
// absmax). Bias now added once AFTER the butterfly. Everything else is R24:
// contiguous wave-ownership (wave w streams kk=8w+i, owns j in [16w,16w+16)),
// fp32 partials, 4 barriers/eval, W1 124-LDS/4-streamed, bounded unroll 4.
__global__ __launch_bounds__(NTH) void node_integrate(
    const float* __restrict__ ts, const float* __restrict__ xs,
    const float* __restrict__ a_sample,
    const float* __restrict__ b0g, const float* __restrict__ b1g,
    const float* __restrict__ b2g, const float* __restrict__ b3g,
    const unsigned* __restrict__ wsu, float* __restrict__ out) {
  HIP_DYNAMIC_SHARED(unsigned, sm);
  float* smf = (float*)sm;
  const int b = blockIdx.x;
  const int tid = threadIdx.x;
  const int w = tid >> 6, l = tid & 63;
  const int g = l >> 2, s = l & 3;
  const int jg = 16 * w + g;            // owned main output, < 256

  // stage W1 pairs 0..123 into LDS
  {
    const uint4* src = (const uint4*)(wsu + WS_W1);
    uint4* dst = (uint4*)(sm + L_W1);
    for (int i = tid; i < NW1LDS * 64; i += NTH) dst[i] = src[i];
  }
  const float rb0 = b0g[jg], rb1 = b1g[jg], rb2 = b2g[jg], rb3 = b3g[jg];
  const int jt = 256 + 2 * w + (l >> 2);            // tail j (w<4, l<8)
  const float rb3t = (w < 4 && l < 8) ? b3g[jt] : 0.f;

  const float sc = a_sample[b] * expf(-0.1f * ts[0]);
  float y_g = sc * sinf(PI_F * xs[(size_t)b * DATA + jg]);
  float acc_g = 0.f, fv = y_g;
  float y_t = 0.f, acc_t = 0.f, fvt = 0.f;

  {
    const float fo = __shfl_xor(fv, 4);
    if ((l & 7) == 0) sm[L_FPH + w * 9 + (l >> 3)] = pkh(fv, fo);
    if (l == 0) sm[L_FPH + w * 9 + 8] = 0u;          // aug dims start at 0
  }
  __syncthreads();
  if (s == 0) out[((size_t)b * NT) * DATA + jg] = y_g;

  const uint4* w0b4 = (const uint4*)(wsu + WS_W0);
  const uint4* w1g4 = (const uint4*)(wsu + WS_W1);
  const uint4* w2b4 = (const uint4*)(wsu + WS_W2);
  const uint4* w3b4 = (const uint4*)(wsu + WS_W3);
  const uint4* w3t4 = (const uint4*)(wsu + WS_W3T);
  const uint4* w1l4 = (const uint4*)(sm + L_W1);

#pragma unroll 1
  for (int t = 0; t < NT - 1; ++t) {
    const float dt = ts[t + 1] - ts[t];
    const float h = dt * (1.0f / NSUB);
#pragma unroll 1
    for (int sub = 0; sub < NSUB; ++sub) {
#pragma unroll 1
      for (int st = 0; st < 3; ++st) {
        // ---- L0 stream -> psA (+ tail pairs kk=128..131 by waves 0..3)
        {
          float4 acc; acc.x = acc.y = acc.z = acc.w = 0.f;
#pragma unroll 4
          for (int i = 0; i < 8; ++i) {
            const int kk = 8 * w + i;
            const uint4 u = w0b4[kk * 64 + l];
            const unsigned hp = sm[L_FPH + w * 9 + i];
            DOT4(acc, u, hp)
          }
          if (w < 4) {
            const int kk = 128 + w;
            const uint4 u = w0b4[kk * 64 + l];
            const unsigned hp = sm[L_FPH + w * 9 + 8];
            DOT4(acc, u, hp)
          }
          ((float4*)(smf + L_PSA + w * 256))[l] = acc;
        }
        __syncthreads();                              // bar1
        // ---- L0 reduce -> FPH (bias added ONCE, after butterfly)
        {
          float sv = 0.f;
#pragma unroll
          for (int p = s; p < 16; p += 4) sv += smf[L_PSA + p * 256 + jg];
          sv += __shfl_xor(sv, 1); sv += __shfl_xor(sv, 2);
          const float hv = tanhf(sv + rb0);
          const float ho = __shfl_xor(hv, 4);
          if ((l & 7) == 0) sm[L_FPH + w * 9 + (l >> 3)] = pkh(hv, ho);
        }
        // ---- L1 stream (LDS W1 + 4 streamed pairs) -> psB
        {
          float4 acc; acc.x = acc.y = acc.z = acc.w = 0.f;
#pragma unroll 4
          for (int i = 0; i < 8; ++i) {
            const int kk = 8 * w + i;
            uint4 u;
            if (kk < NW1LDS) u = w1l4[kk * 64 + l];
            else             u = w1g4[kk * 64 + l];
            const unsigned hp = sm[L_FPH + w * 9 + i];
            DOT4(acc, u, hp)
          }
          ((float4*)(smf + L_PSB + w * 256))[l] = acc;
        }
        __syncthreads();                              // bar2
        // ---- L1 reduce -> FPH
        {
          float sv = 0.f;
#pragma unroll
          for (int p = s; p < 16; p += 4) sv += smf[L_PSB + p * 256 + jg];
          sv += __shfl_xor(sv, 1); sv += __shfl_xor(sv, 2);
          const float hv = tanhf(sv + rb1);
          const float ho = __shfl_xor(hv, 4);
          if ((l & 7) == 0) sm[L_FPH + w * 9 + (l >> 3)] = pkh(hv, ho);
        }
        // ---- L2 stream -> psA
        {
          float4 acc; acc.x = acc.y = acc.z = acc.w = 0.f;
#pragma unroll 4
          for (int i = 0; i < 8; ++i) {
            const int kk = 8 * w + i;
            const uint4 u = w2b4[kk * 64 + l];
            const unsigned hp = sm[L_FPH + w * 9 + i];
            DOT4(acc, u, hp)
          }
          ((float4*)(smf + L_PSA + w * 256))[l] = acc;
        }
        __syncthreads();                              // bar3
        // ---- L2 reduce -> FPH
        {
          float sv = 0.f;
#pragma unroll
          for (int p = s; p < 16; p += 4) sv += smf[L_PSA + p * 256 + jg];
          sv += __shfl_xor(sv, 1); sv += __shfl_xor(sv, 2);
          const float hv = tanhf(sv + rb2);
          const float ho = __shfl_xor(hv, 4);
          if ((l & 7) == 0) sm[L_FPH + w * 9 + (l >> 3)] = pkh(hv, ho);
        }
        // ---- L3 stream -> psB + tail partials -> PT
        {
          float4 acc; acc.x = acc.y = acc.z = acc.w = 0.f;
#pragma unroll 4
          for (int i = 0; i < 8; ++i) {
            const int kk = 8 * w + i;
            const uint4 u = w3b4[kk * 64 + l];
            const unsigned hp = sm[L_FPH + w * 9 + i];
            DOT4(acc, u, hp)
          }
          ((float4*)(smf + L_PSB + w * 256))[l] = acc;
          if (l < 2) {
            float4 accx; accx.x = accx.y = accx.z = accx.w = 0.f;
#pragma unroll 4
            for (int i = 0; i < 8; ++i) {
              const int kk = 8 * w + i;
              const uint4 u = w3t4[kk * 2 + l];
              const unsigned hp = sm[L_FPH + w * 9 + i];
              DOT4(accx, u, hp)
            }
            ((float4*)(smf + L_PT + w * 8))[l] = accx;
          }
        }
        __syncthreads();                              // bar4
        // ---- L3 reduce + RK (registers) + repack FPH
        {
          float sv = 0.f;
#pragma unroll
          for (int p = s; p < 16; p += 4) sv += smf[L_PSB + p * 256 + jg];
          sv += __shfl_xor(sv, 1); sv += __shfl_xor(sv, 2);
          const float kv = sv + rb3;
          float svt = 0.f;
          if (w < 4 && l < 8) {
#pragma unroll
            for (int tt = 0; tt < 4; ++tt) {
              const int p = (l & 3) + 4 * tt;
              svt += smf[L_PT + p * 8 + 2 * w + (l >> 2)];
            }
          }
          svt += __shfl_xor(svt, 1); svt += __shfl_xor(svt, 2);
          const float kvt = svt + rb3t;
          if (st == 0) {
            acc_g = (2.0f / 9.0f) * kv;
            fv = y_g + 0.5f * h * kv;
            acc_t = (2.0f / 9.0f) * kvt;
            fvt = y_t + 0.5f * h * kvt;
          } else if (st == 1) {
            acc_g += (1.0f / 3.0f) * kv;
            fv = y_g + 0.75f * h * kv;
            acc_t += (1.0f / 3.0f) * kvt;
            fvt = y_t + 0.75f * h * kvt;
          } else {
            y_g += h * (acc_g + (4.0f / 9.0f) * kv);
            fv = y_g;
            y_t += h * (acc_t + (4.0f / 9.0f) * kvt);
            fvt = y_t;
          }
          const float fo = __shfl_xor(fv, 4);
          if ((l & 7) == 0) sm[L_FPH + w * 9 + (l >> 3)] = pkh(fv, fo);
          const float fot = __shfl_xor(fvt, 4);
          if (l == 0) sm[L_FPH + w * 9 + 8] = (w < 4) ? pkh(fvt, fot) : 0u;
        }
      }
    }
    if (s == 0) out[((size_t)b * NT + (t + 1)) * DATA + jg] = y_g;
  }
}

extern "C" void kernel_launch(void* const* d_in, const int* in_sizes, int n_in,
                              void* d_out, int out_size, void* d_ws, size_t ws_size,
                              hipStream_t stream) {
  const float* ts = (const float*)d_in[0];
  const float* xs = (const float*)d_in[1];
  const float* a  = (const float*)d_in[2];
  const float* W0 = (const float*)d_in[3];
  const float* b0 = (const float*)d_in[4];
  const float* W1 = (const float*)d_in[5];
  const float* b1 = (const float*)d_in[6];
  const float* W2 = (const float*)d_in[7];
  const float* b2 = (const float*)d_in[8];
  const float* W3 = (const float*)d_in[9];
  const float* b3 = (const float*)d_in[10];
  unsigned* ws = (unsigned*)d_ws;
  float* out = (float*)d_out;

  const size_t lds_bytes = LDS_WORDS * sizeof(unsigned);
  (void)hipFuncSetAttribute(reinterpret_cast<const void*>(node_integrate),
                            hipFuncAttributeMaxDynamicSharedMemorySize,
                            (int)lds_bytes);

  hipLaunchKernelGGL(prep, dim3(256), dim3(256), 0, stream, W0, W1, W2, W3, ws);
  hipLaunchKernelGGL(node_integrate, dim3(NB), dim3(NTH), lds_bytes, stream,
                     ts, xs, a, b0, b1, b2, b3, ws, out);
}

// Round 26
// 4980.312 us; speedup vs baseline: 1.0455x; 1.0455x over previous
//
#include <hip/hip_runtime.h>
#include <cmath>

#define NB   256
#define NT   64
#define DATA 256
#define DD   264
#define NSUB 4
#define NTH  1024
#define PSS  272   // PS row stride in floats: 272 % 32 = 16 -> 2-way (free) banks
#define PI_F 3.14159265358979323846f

typedef _Float16 h2 __attribute__((ext_vector_type(2)));
typedef __fp16   g2 __attribute__((ext_vector_type(2)));

// ---- d_ws u32 offsets: f16 pairs ALONG K (u32 [kk][j] = {W[2kk][j],W[2kk+1][j]})
#define WS_W0  0                        // [136][256]
#define WS_W1  (WS_W0 + 136 * 256)      // [128][256]
#define WS_W2  (WS_W1 + 128 * 256)      // [128][256]
#define WS_W3  (WS_W2 + 128 * 256)      // [128][256]
#define WS_W3T (WS_W3 + 128 * 256)      // [128][8]  tail j=256..263

// ---- LDS word offsets ----
#define NW1LDS 124                        // W1 pairs resident in LDS
#define L_W1   0                          // [124][256] u32 = 126,976 B
#define L_PSA  (L_W1 + NW1LDS * 256)      // [16][272] fp32 partials (buffer A)
#define L_PSB  (L_PSA + 16 * PSS)         // [16][272] fp32 partials (buffer B)
#define L_PT   (L_PSB + 16 * PSS)         // [16][8]   fp32 tail partials
#define L_FPH  (L_PT + 16 * 8)            // [16][9]   packed f16 activations
#define LDS_WORDS (L_FPH + 16 * 9)        // 40,720 words = 162,880 B -> 1 blk/CU

__device__ __forceinline__ float dot2(unsigned wu, unsigned hu, float c) {
  h2 a = __builtin_bit_cast(h2, wu);
  h2 b = __builtin_bit_cast(h2, hu);
#if __has_builtin(__builtin_amdgcn_fdot2)
  return __builtin_amdgcn_fdot2(a, b, c, false);
#else
  return c + (float)a[0] * (float)b[0] + (float)a[1] * (float)b[1];
#endif
}
__device__ __forceinline__ unsigned pkh(float a, float b) {
#if __has_builtin(__builtin_amdgcn_cvt_pkrtz)
  g2 v = __builtin_amdgcn_cvt_pkrtz(a, b);
  return __builtin_bit_cast(unsigned, v);
#else
  h2 v; v[0] = (_Float16)a; v[1] = (_Float16)b;
  return __builtin_bit_cast(unsigned, v);
#endif
}
__device__ __forceinline__ unsigned pkh_rne(float a, float b) {
  h2 v; v[0] = (_Float16)a; v[1] = (_Float16)b;
  return __builtin_bit_cast(unsigned, v);
}

#define DOT4(acc, u, hp)                                                      \
  acc.x = dot2(u.x, hp, acc.x);                                               \
  acc.y = dot2(u.y, hp, acc.y);                                               \
  acc.z = dot2(u.z, hp, acc.z);                                               \
  acc.w = dot2(u.w, hp, acc.w);

__global__ void prep(const float* __restrict__ W0, const float* __restrict__ W1,
                     const float* __restrict__ W2, const float* __restrict__ W3,
                     unsigned* __restrict__ wsu) {
  int tid = blockIdx.x * blockDim.x + threadIdx.x;
  int stride = gridDim.x * blockDim.x;
  for (int i = tid; i < 136 * 256; i += stride) {
    int kk = i >> 8, j = i & 255;
    int k0 = 2 * kk, k1 = 2 * kk + 1;
    float lo = (k0 < DD) ? W0[j * DD + k0] : 0.f;
    float hi = (k1 < DD) ? W0[j * DD + k1] : 0.f;
    wsu[WS_W0 + i] = pkh_rne(lo, hi);
  }
  for (int i = tid; i < 128 * 256; i += stride) {
    int kk = i >> 8, j = i & 255;
    wsu[WS_W1 + i] = pkh_rne(W1[j * 256 + 2 * kk], W1[j * 256 + 2 * kk + 1]);
    wsu[WS_W2 + i] = pkh_rne(W2[j * 256 + 2 * kk], W2[j * 256 + 2 * kk + 1]);
    wsu[WS_W3 + i] = pkh_rne(W3[j * 256 + 2 * kk], W3[j * 256 + 2 * kk + 1]);
  }
  for (int i = tid; i < 128 * 8; i += stride) {     // W3 tail j=256..263
    int kk = i >> 3, c = 256 + (i & 7);
    wsu[WS_W3T + i] = pkh_rne(W3[c * 256 + 2 * kk], W3[c * 256 + 2 * kk + 1]);
  }
}

// R26 = R25 (verified numerics) with PS row stride 256 -> 272 floats.
// 256 % 32 == 0 made the 4 reduce lanes of each output group hit ONE bank
// (4-way conflict, 2.97e8 cycles). 272 % 32 == 16 -> bank = (16s+g)%32,
// exactly 2-way per bank, which is free on CDNA4 (m136).
__global__ __launch_bounds__(NTH) void node_integrate(
    const float* __restrict__ ts, const float* __restrict__ xs,
    const float* __restrict__ a_sample,
    const float* __restrict__ b0g, const float* __restrict__ b1g,
    const float* __restrict__ b2g, const float* __restrict__ b3g,
    const unsigned* __restrict__ wsu, float* __restrict__ out) {
  HIP_DYNAMIC_SHARED(unsigned, sm);
  float* smf = (float*)sm;
  const int b = blockIdx.x;
  const int tid = threadIdx.x;
  const int w = tid >> 6, l = tid & 63;
  const int g = l >> 2, s = l & 3;
  const int jg = 16 * w + g;            // owned main output, < 256

  // stage W1 pairs 0..123 into LDS
  {
    const uint4* src = (const uint4*)(wsu + WS_W1);
    uint4* dst = (uint4*)(sm + L_W1);
    for (int i = tid; i < NW1LDS * 64; i += NTH) dst[i] = src[i];
  }
  const float rb0 = b0g[jg], rb1 = b1g[jg], rb2 = b2g[jg], rb3 = b3g[jg];
  const int jt = 256 + 2 * w + (l >> 2);            // tail j (w<4, l<8)
  const float rb3t = (w < 4 && l < 8) ? b3g[jt] : 0.f;

  const float sc = a_sample[b] * expf(-0.1f * ts[0]);
  float y_g = sc * sinf(PI_F * xs[(size_t)b * DATA + jg]);
  float acc_g = 0.f, fv = y_g;
  float y_t = 0.f, acc_t = 0.f, fvt = 0.f;

  {
    const float fo = __shfl_xor(fv, 4);
    if ((l & 7) == 0) sm[L_FPH + w * 9 + (l >> 3)] = pkh(fv, fo);
    if (l == 0) sm[L_FPH + w * 9 + 8] = 0u;          // aug dims start at 0
  }
  __syncthreads();
  if (s == 0) out[((size_t)b * NT) * DATA + jg] = y_g;

  const uint4* w0b4 = (const uint4*)(wsu + WS_W0);
  const uint4* w1g4 = (const uint4*)(wsu + WS_W1);
  const uint4* w2b4 = (const uint4*)(wsu + WS_W2);
  const uint4* w3b4 = (const uint4*)(wsu + WS_W3);
  const uint4* w3t4 = (const uint4*)(wsu + WS_W3T);
  const uint4* w1l4 = (const uint4*)(sm + L_W1);

#pragma unroll 1
  for (int t = 0; t < NT - 1; ++t) {
    const float dt = ts[t + 1] - ts[t];
    const float h = dt * (1.0f / NSUB);
#pragma unroll 1
    for (int sub = 0; sub < NSUB; ++sub) {
#pragma unroll 1
      for (int st = 0; st < 3; ++st) {
        // ---- L0 stream -> psA (+ tail pairs kk=128..131 by waves 0..3)
        {
          float4 acc; acc.x = acc.y = acc.z = acc.w = 0.f;
#pragma unroll 4
          for (int i = 0; i < 8; ++i) {
            const int kk = 8 * w + i;
            const uint4 u = w0b4[kk * 64 + l];
            const unsigned hp = sm[L_FPH + w * 9 + i];
            DOT4(acc, u, hp)
          }
          if (w < 4) {
            const int kk = 128 + w;
            const uint4 u = w0b4[kk * 64 + l];
            const unsigned hp = sm[L_FPH + w * 9 + 8];
            DOT4(acc, u, hp)
          }
          ((float4*)(smf + L_PSA + w * PSS))[l] = acc;
        }
        __syncthreads();                              // bar1
        // ---- L0 reduce -> FPH (bias once, after butterfly)
        {
          float sv = 0.f;
#pragma unroll
          for (int p = s; p < 16; p += 4) sv += smf[L_PSA + p * PSS + jg];
          sv += __shfl_xor(sv, 1); sv += __shfl_xor(sv, 2);
          const float hv = tanhf(sv + rb0);
          const float ho = __shfl_xor(hv, 4);
          if ((l & 7) == 0) sm[L_FPH + w * 9 + (l >> 3)] = pkh(hv, ho);
        }
        // ---- L1 stream (LDS W1 + 4 streamed pairs) -> psB
        {
          float4 acc; acc.x = acc.y = acc.z = acc.w = 0.f;
#pragma unroll 4
          for (int i = 0; i < 8; ++i) {
            const int kk = 8 * w + i;
            uint4 u;
            if (kk < NW1LDS) u = w1l4[kk * 64 + l];
            else             u = w1g4[kk * 64 + l];
            const unsigned hp = sm[L_FPH + w * 9 + i];
            DOT4(acc, u, hp)
          }
          ((float4*)(smf + L_PSB + w * PSS))[l] = acc;
        }
        __syncthreads();                              // bar2
        // ---- L1 reduce -> FPH
        {
          float sv = 0.f;
#pragma unroll
          for (int p = s; p < 16; p += 4) sv += smf[L_PSB + p * PSS + jg];
          sv += __shfl_xor(sv, 1); sv += __shfl_xor(sv, 2);
          const float hv = tanhf(sv + rb1);
          const float ho = __shfl_xor(hv, 4);
          if ((l & 7) == 0) sm[L_FPH + w * 9 + (l >> 3)] = pkh(hv, ho);
        }
        // ---- L2 stream -> psA
        {
          float4 acc; acc.x = acc.y = acc.z = acc.w = 0.f;
#pragma unroll 4
          for (int i = 0; i < 8; ++i) {
            const int kk = 8 * w + i;
            const uint4 u = w2b4[kk * 64 + l];
            const unsigned hp = sm[L_FPH + w * 9 + i];
            DOT4(acc, u, hp)
          }
          ((float4*)(smf + L_PSA + w * PSS))[l] = acc;
        }
        __syncthreads();                              // bar3
        // ---- L2 reduce -> FPH
        {
          float sv = 0.f;
#pragma unroll
          for (int p = s; p < 16; p += 4) sv += smf[L_PSA + p * PSS + jg];
          sv += __shfl_xor(sv, 1); sv += __shfl_xor(sv, 2);
          const float hv = tanhf(sv + rb2);
          const float ho = __shfl_xor(hv, 4);
          if ((l & 7) == 0) sm[L_FPH + w * 9 + (l >> 3)] = pkh(hv, ho);
        }
        // ---- L3 stream -> psB + tail partials -> PT
        {
          float4 acc; acc.x = acc.y = acc.z = acc.w = 0.f;
#pragma unroll 4
          for (int i = 0; i < 8; ++i) {
            const int kk = 8 * w + i;
            const uint4 u = w3b4[kk * 64 + l];
            const unsigned hp = sm[L_FPH + w * 9 + i];
            DOT4(acc, u, hp)
          }
          ((float4*)(smf + L_PSB + w * PSS))[l] = acc;
          if (l < 2) {
            float4 accx; accx.x = accx.y = accx.z = accx.w = 0.f;
#pragma unroll 4
            for (int i = 0; i < 8; ++i) {
              const int kk = 8 * w + i;
              const uint4 u = w3t4[kk * 2 + l];
              const unsigned hp = sm[L_FPH + w * 9 + i];
              DOT4(accx, u, hp)
            }
            ((float4*)(smf + L_PT + w * 8))[l] = accx;
          }
        }
        __syncthreads();                              // bar4
        // ---- L3 reduce + RK (registers) + repack FPH
        {
          float sv = 0.f;
#pragma unroll
          for (int p = s; p < 16; p += 4) sv += smf[L_PSB + p * PSS + jg];
          sv += __shfl_xor(sv, 1); sv += __shfl_xor(sv, 2);
          const float kv = sv + rb3;
          float svt = 0.f;
          if (w < 4 && l < 8) {
#pragma unroll
            for (int tt = 0; tt < 4; ++tt) {
              const int p = (l & 3) + 4 * tt;
              svt += smf[L_PT + p * 8 + 2 * w + (l >> 2)];
            }
          }
          svt += __shfl_xor(svt, 1); svt += __shfl_xor(svt, 2);
          const float kvt = svt + rb3t;
          if (st == 0) {
            acc_g = (2.0f / 9.0f) * kv;
            fv = y_g + 0.5f * h * kv;
            acc_t = (2.0f / 9.0f) * kvt;
            fvt = y_t + 0.5f * h * kvt;
          } else if (st == 1) {
            acc_g += (1.0f / 3.0f) * kv;
            fv = y_g + 0.75f * h * kv;
            acc_t += (1.0f / 3.0f) * kvt;
            fvt = y_t + 0.75f * h * kvt;
          } else {
            y_g += h * (acc_g + (4.0f / 9.0f) * kv);
            fv = y_g;
            y_t += h * (acc_t + (4.0f / 9.0f) * kvt);
            fvt = y_t;
          }
          const float fo = __shfl_xor(fv, 4);
          if ((l & 7) == 0) sm[L_FPH + w * 9 + (l >> 3)] = pkh(fv, fo);
          const float fot = __shfl_xor(fvt, 4);
          if (l == 0) sm[L_FPH + w * 9 + 8] = (w < 4) ? pkh(fvt, fot) : 0u;
        }
      }
    }
    if (s == 0) out[((size_t)b * NT + (t + 1)) * DATA + jg] = y_g;
  }
}

extern "C" void kernel_launch(void* const* d_in, const int* in_sizes, int n_in,
                              void* d_out, int out_size, void* d_ws, size_t ws_size,
                              hipStream_t stream) {
  const float* ts = (const float*)d_in[0];
  const float* xs = (const float*)d_in[1];
  const float* a  = (const float*)d_in[2];
  const float* W0 = (const float*)d_in[3];
  const float* b0 = (const float*)d_in[4];
  const float* W1 = (const float*)d_in[5];
  const float* b1 = (const float*)d_in[6];
  const float* W2 = (const float*)d_in[7];
  const float* b2 = (const float*)d_in[8];
  const float* W3 = (const float*)d_in[9];
  const float* b3 = (const float*)d_in[10];
  unsigned* ws = (unsigned*)d_ws;
  float* out = (float*)d_out;

  const size_t lds_bytes = LDS_WORDS * sizeof(unsigned);
  (void)hipFuncSetAttribute(reinterpret_cast<const void*>(node_integrate),
                            hipFuncAttributeMaxDynamicSharedMemorySize,
                            (int)lds_bytes);

  hipLaunchKernelGGL(prep, dim3(256), dim3(256), 0, stream, W0, W1, W2, W3, ws);
  hipLaunchKernelGGL(node_integrate, dim3(NB), dim3(NTH), lds_bytes, stream,
                     ts, xs, a, b0, b1, b2, b3, ws, out);
}